// Round 1
// baseline (41.359 us; speedup 1.0000x reference)
//
#include <hip/hip_runtime.h>

#define NQ 11
#define NST (1 << NQ)       // 2048 amplitudes
#define NPAIR (NST / 2)     // 1024 pairs for a 1q gate
#define NC 3
#define NANG (NC * 66)      // 198 angles
#define BLOCK 256

__global__ __launch_bounds__(BLOCK) void qsim_kernel(
    const float* __restrict__ x, const float* __restrict__ W,
    const float* __restrict__ bias, float* __restrict__ out) {
  const int bidx = blockIdx.x;   // batch element
  const int tid = threadIdx.x;

  __shared__ float sre[NST];
  __shared__ float sim_[NST];
  __shared__ float ang[NANG];
  __shared__ float xs[NQ];
  __shared__ float m1[NC * NQ][8];   // fused 1q matrices (complex 2x2)
  __shared__ float m2[NC * NQ][8];   // fused controlled matrices
  __shared__ float redx[NQ][4];
  __shared__ float redz[NQ][4];

  // ---- load x row ----
  if (tid < NQ) xs[tid] = x[bidx * NQ + tid];
  __syncthreads();

  // ---- angles: ang[c*66 + rot*11 + q] = W[c,o,:]·x + b[c,o] ----
  if (tid < NANG) {
    const int c = tid / 66, o = tid - c * 66;
    const float* wr = W + (c * 66 + o) * NQ;
    float s = bias[c * 66 + o];
#pragma unroll
    for (int i = 0; i < NQ; ++i) s += wr[i] * xs[i];
    ang[tid] = s;
  }
  // ---- init state |0...0> ----
  for (int k = tid; k < NST; k += BLOCK) { sre[k] = 0.f; sim_[k] = 0.f; }
  __syncthreads();
  if (tid == 0) sre[0] = 1.f;

  // ---- precompute fused matrices ----
  if (tid < 2 * NC * NQ) {
    const int kind = tid / (NC * NQ);
    const int id = tid - kind * (NC * NQ);
    const int c = id / NQ, q = id - c * NQ;
    const float* a = ang + c * 66;
    if (kind == 0) {
      // U = RZ(a3) RY(a2) RZ(a1) RY(a0)
      float s0, c0, s1, c1, s2, c2, s3, c3;
      sincosf(0.5f * a[q],        &s0, &c0);
      sincosf(0.5f * a[11 + q],   &s1, &c1);
      sincosf(0.5f * a[22 + q],   &s2, &c2);
      sincosf(0.5f * a[33 + q],   &s3, &c3);
      // M1 = RZ(a1) RY(a0); e0 = c1 - i s1
      float m00r = c1 * c0, m00i = -s1 * c0;
      float m01r = -c1 * s0, m01i = s1 * s0;
      float m10r = c1 * s0, m10i = s1 * s0;
      float m11r = c1 * c0, m11i = s1 * c0;
      // M2 = RY(a2) M1
      float n00r = c2 * m00r - s2 * m10r, n00i = c2 * m00i - s2 * m10i;
      float n01r = c2 * m01r - s2 * m11r, n01i = c2 * m01i - s2 * m11i;
      float n10r = s2 * m00r + c2 * m10r, n10i = s2 * m00i + c2 * m10i;
      float n11r = s2 * m01r + c2 * m11r, n11i = s2 * m01i + c2 * m11i;
      // U = RZ(a3) M2 : row0 *= (c3 - i s3), row1 *= (c3 + i s3)
      m1[id][0] = c3 * n00r + s3 * n00i; m1[id][1] = c3 * n00i - s3 * n00r;
      m1[id][2] = c3 * n01r + s3 * n01i; m1[id][3] = c3 * n01i - s3 * n01r;
      m1[id][4] = c3 * n10r - s3 * n10i; m1[id][5] = c3 * n10i + s3 * n10r;
      m1[id][6] = c3 * n11r - s3 * n11i; m1[id][7] = c3 * n11i + s3 * n11r;
    } else {
      // U = RZ(a5) RY(a4); e = c5 - i s5
      float s4, c4, s5, c5;
      sincosf(0.5f * a[44 + q], &s4, &c4);
      sincosf(0.5f * a[55 + q], &s5, &c5);
      m2[id][0] = c5 * c4;  m2[id][1] = -s5 * c4;
      m2[id][2] = -c5 * s4; m2[id][3] = s5 * s4;
      m2[id][4] = c5 * s4;  m2[id][5] = s5 * s4;
      m2[id][6] = c5 * c4;  m2[id][7] = s5 * c4;
    }
  }
  __syncthreads();

  // ---- circuits ----
  for (int c = 0; c < NC; ++c) {
    // fused single-qubit layer
    for (int q = 0; q < NQ; ++q) {
      const float* U = m1[c * NQ + q];
      const float u00r = U[0], u00i = U[1], u01r = U[2], u01i = U[3];
      const float u10r = U[4], u10i = U[5], u11r = U[6], u11i = U[7];
      const int bp = NQ - 1 - q, st = 1 << bp, lm = st - 1;
      for (int p = tid; p < NPAIR; p += BLOCK) {
        const int i0 = ((p & ~lm) << 1) | (p & lm);
        const int i1 = i0 | st;
        const float r0 = sre[i0], q0 = sim_[i0];
        const float r1 = sre[i1], q1 = sim_[i1];
        sre[i0]  = u00r * r0 - u00i * q0 + u01r * r1 - u01i * q1;
        sim_[i0] = u00r * q0 + u00i * r0 + u01r * q1 + u01i * r1;
        sre[i1]  = u10r * r0 - u10i * q0 + u11r * r1 - u11i * q1;
        sim_[i1] = u10r * q0 + u10i * r0 + u11r * q1 + u11i * r1;
      }
      __syncthreads();
    }
    // fused controlled layer: control q, target (q+1)%NQ
    for (int q = 0; q < NQ; ++q) {
      const int t = (q + 1) % NQ;
      const float* U = m2[c * NQ + q];
      const float u00r = U[0], u00i = U[1], u01r = U[2], u01i = U[3];
      const float u10r = U[4], u10i = U[5], u11r = U[6], u11i = U[7];
      const int bc = NQ - 1 - q, bt = NQ - 1 - t;
      const int blo = bc < bt ? bc : bt;
      const int bhi = bc < bt ? bt : bc;
      const int mlo = (1 << blo) - 1;
      const int nmid = bhi - blo - 1;
      const int mmid = (1 << nmid) - 1;
      for (int p = tid; p < NPAIR / 2; p += BLOCK) {
        const int low = p & mlo;
        const int mid = (p >> blo) & mmid;
        const int high = p >> (blo + nmid);
        const int i0 = low | (mid << (blo + 1)) | (high << (bhi + 1)) | (1 << bc);
        const int i1 = i0 | (1 << bt);
        const float r0 = sre[i0], q0 = sim_[i0];
        const float r1 = sre[i1], q1 = sim_[i1];
        sre[i0]  = u00r * r0 - u00i * q0 + u01r * r1 - u01i * q1;
        sim_[i0] = u00r * q0 + u00i * r0 + u01r * q1 + u01i * r1;
        sre[i1]  = u10r * r0 - u10i * q0 + u11r * r1 - u11i * q1;
        sim_[i1] = u10r * q0 + u10i * r0 + u11r * q1 + u11i * r1;
      }
      __syncthreads();
    }
  }

  // ---- expectation values ----
  const int wave = tid >> 6, lane = tid & 63;
  for (int q = 0; q < NQ; ++q) {
    const int bp = NQ - 1 - q, st = 1 << bp, lm = st - 1;
    float xacc = 0.f, zacc = 0.f;
    for (int p = tid; p < NPAIR; p += BLOCK) {
      const int i0 = ((p & ~lm) << 1) | (p & lm);
      const int i1 = i0 | st;
      const float r0 = sre[i0], q0 = sim_[i0];
      const float r1 = sre[i1], q1 = sim_[i1];
      xacc += r0 * r1 + q0 * q1;
      zacc += (r0 * r0 + q0 * q0) - (r1 * r1 + q1 * q1);
    }
#pragma unroll
    for (int off = 32; off; off >>= 1) {
      xacc += __shfl_down(xacc, off);
      zacc += __shfl_down(zacc, off);
    }
    if (lane == 0) { redx[q][wave] = xacc; redz[q][wave] = zacc; }
  }
  __syncthreads();
  if (tid < 2 * NQ) {
    const int q = tid < NQ ? tid : tid - NQ;
    const bool isz = tid >= NQ;
    float s = 0.f;
#pragma unroll
    for (int w = 0; w < 4; ++w) s += isz ? redz[q][w] : redx[q][w];
    out[bidx * 2 * NQ + tid] = isz ? s : 2.f * s;
  }
}

extern "C" void kernel_launch(void* const* d_in, const int* in_sizes, int n_in,
                              void* d_out, int out_size, void* d_ws, size_t ws_size,
                              hipStream_t stream) {
  (void)n_in; (void)d_ws; (void)ws_size; (void)out_size;
  const float* x = (const float*)d_in[0];
  const float* W = (const float*)d_in[1];
  const float* b = (const float*)d_in[2];
  float* out = (float*)d_out;
  const int batch = in_sizes[0] / NQ;
  qsim_kernel<<<batch, BLOCK, 0, stream>>>(x, W, b, out);
}

// Round 2
// 38.149 us; speedup vs baseline: 1.0841x; 1.0841x over previous
//
#include <hip/hip_runtime.h>

#define NQ 11
#define NC 3
#define NANG (NC * 66)
#define BLOCK 256

struct Mat { float u00r,u00i,u01r,u01i,u10r,u10i,u11r,u11i; };

__device__ __forceinline__ Mat loadU(const float4* __restrict__ p) {
  float4 a = p[0], b = p[1];
  Mat m; m.u00r=a.x; m.u00i=a.y; m.u01r=a.z; m.u01i=a.w;
  m.u10r=b.x; m.u10i=b.y; m.u11r=b.z; m.u11i=b.w; return m;
}

// ---- 1q gate on register bit RB ----
template<int RB>
__device__ __forceinline__ void g_reg(float (&sr)[8], float (&si)[8], const Mat& U) {
#pragma unroll
  for (int i = 0; i < 8; ++i) {
    if (i & (1 << RB)) continue;
    const int j = i | (1 << RB);
    const float r0=sr[i], q0=si[i], r1=sr[j], q1=si[j];
    sr[i]=U.u00r*r0-U.u00i*q0+U.u01r*r1-U.u01i*q1;
    si[i]=U.u00r*q0+U.u00i*r0+U.u01r*q1+U.u01i*r1;
    sr[j]=U.u10r*r0-U.u10i*q0+U.u11r*r1-U.u11i*q1;
    si[j]=U.u10r*q0+U.u10i*r0+U.u11r*q1+U.u11i*r1;
  }
}

// ---- controlled: control reg bit CB, target reg bit TB ----
template<int CB, int TB>
__device__ __forceinline__ void g_creg(float (&sr)[8], float (&si)[8], const Mat& U) {
#pragma unroll
  for (int i = 0; i < 8; ++i) {
    if (!(i & (1 << CB)) || (i & (1 << TB))) continue;
    const int j = i | (1 << TB);
    const float r0=sr[i], q0=si[i], r1=sr[j], q1=si[j];
    sr[i]=U.u00r*r0-U.u00i*q0+U.u01r*r1-U.u01i*q1;
    si[i]=U.u00r*q0+U.u00i*r0+U.u01r*q1+U.u01i*r1;
    sr[j]=U.u10r*r0-U.u10i*q0+U.u11r*r1-U.u11i*q1;
    si[j]=U.u10r*q0+U.u10i*r0+U.u11r*q1+U.u11i*r1;
  }
}

// ---- 1q (optionally per-lane controlled) on lane bit LB ----
template<int LB, bool CTRL>
__device__ __forceinline__ void g_lane(float (&sr)[8], float (&si)[8], const Mat& U,
                                       int lane, bool cv) {
  const bool low = ((lane >> LB) & 1) == 0;
  float cor = low?U.u00r:U.u11r, coi = low?U.u00i:U.u11i;   // coeff on own amp
  float cpr = low?U.u01r:U.u10r, cpi = low?U.u01i:U.u10i;   // coeff on partner amp
  if (CTRL) { cor = cv?cor:1.f; coi = cv?coi:0.f; cpr = cv?cpr:0.f; cpi = cv?cpi:0.f; }
#pragma unroll
  for (int i = 0; i < 8; ++i) {
    const float pr = __shfl_xor(sr[i], 1 << LB, 64);
    const float pi = __shfl_xor(si[i], 1 << LB, 64);
    const float nr = cor*sr[i]-coi*si[i]+cpr*pr-cpi*pi;
    const float ni = cor*si[i]+coi*sr[i]+cpr*pi+cpi*pr;
    sr[i]=nr; si[i]=ni;
  }
}

// ---- controlled by per-lane bool, target reg bit TB ----
template<int TB>
__device__ __forceinline__ void g_clane_reg(float (&sr)[8], float (&si)[8], const Mat& U, bool cv) {
  const float c00r=cv?U.u00r:1.f, c00i=cv?U.u00i:0.f;
  const float c01r=cv?U.u01r:0.f, c01i=cv?U.u01i:0.f;
  const float c10r=cv?U.u10r:0.f, c10i=cv?U.u10i:0.f;
  const float c11r=cv?U.u11r:1.f, c11i=cv?U.u11i:0.f;
#pragma unroll
  for (int i = 0; i < 8; ++i) {
    if (i & (1 << TB)) continue;
    const int j = i | (1 << TB);
    const float r0=sr[i], q0=si[i], r1=sr[j], q1=si[j];
    sr[i]=c00r*r0-c00i*q0+c01r*r1-c01i*q1;
    si[i]=c00r*q0+c00i*r0+c01r*q1+c01i*r1;
    sr[j]=c10r*r0-c10i*q0+c11r*r1-c11i*q1;
    si[j]=c10r*q0+c10i*r0+c11r*q1+c11i*r1;
  }
}

// ---- wave-bit gate via LDS exchange. WX: wave-id xor (1 -> amp bit9, 2 -> amp bit10).
// ODD: only odd register amps participate (control = reg bit0). ----
template<int WX, bool ODD>
__device__ __forceinline__ void g_wave(float (&sr)[8], float (&si)[8], const Mat& U,
                                       float2* __restrict__ buf, int wave, int lane, bool active) {
  const int base = (wave << 6) | lane;
  if (active) {
#pragma unroll
    for (int i = 0; i < 8; ++i) {
      if (ODD && !(i & 1)) continue;
      buf[(i << 8) | base] = make_float2(sr[i], si[i]);
    }
  }
  __syncthreads();
  if (active) {
    const int pbase = ((wave ^ WX) << 6) | lane;
    const int bit = (WX == 2) ? ((wave >> 1) & 1) : (wave & 1);
    const float cor = bit?U.u11r:U.u00r, coi = bit?U.u11i:U.u00i;
    const float cpr = bit?U.u10r:U.u01r, cpi = bit?U.u10i:U.u01i;
#pragma unroll
    for (int i = 0; i < 8; ++i) {
      if (ODD && !(i & 1)) continue;
      const float2 p = buf[(i << 8) | pbase];
      const float nr = cor*sr[i]-coi*si[i]+cpr*p.x-cpi*p.y;
      const float ni = cor*si[i]+coi*sr[i]+cpr*p.y+cpi*p.x;
      sr[i]=nr; si[i]=ni;
    }
  }
}

__global__ __launch_bounds__(BLOCK) void qsim_kernel(
    const float* __restrict__ x, const float* __restrict__ W,
    const float* __restrict__ bias, float* __restrict__ out) {
  const int bidx = blockIdx.x;
  const int tid = threadIdx.x;
  const int lane = tid & 63, wave = tid >> 6;

  __shared__ float xs[NQ];
  __shared__ float ang[NANG];
  __shared__ float4 m1[NC * NQ * 2];
  __shared__ float4 m2[NC * NQ * 2];
  __shared__ float2 ex0[2048];
  __shared__ float2 ex1[2048];
  __shared__ float red[4][22];

  if (tid < NQ) xs[tid] = x[bidx * NQ + tid];
  __syncthreads();

  if (tid < NANG) {
    const int c = tid / 66, o = tid - c * 66;
    const float* wr = W + (c * 66 + o) * NQ;
    float s = bias[c * 66 + o];
#pragma unroll
    for (int i = 0; i < NQ; ++i) s += wr[i] * xs[i];
    ang[tid] = s;
  }
  __syncthreads();

  if (tid < 2 * NC * NQ) {
    const int kind = tid / (NC * NQ);
    const int id = tid - kind * (NC * NQ);
    const int c = id / NQ, q = id - c * NQ;
    const float* a = ang + c * 66;
    if (kind == 0) {
      // U = RZ(a3) RY(a2) RZ(a1) RY(a0)
      float s0, c0, s1, c1, s2, c2, s3, c3;
      sincosf(0.5f * a[q],      &s0, &c0);
      sincosf(0.5f * a[11 + q], &s1, &c1);
      sincosf(0.5f * a[22 + q], &s2, &c2);
      sincosf(0.5f * a[33 + q], &s3, &c3);
      float m00r = c1 * c0, m00i = -s1 * c0;
      float m01r = -c1 * s0, m01i = s1 * s0;
      float m10r = c1 * s0, m10i = s1 * s0;
      float m11r = c1 * c0, m11i = s1 * c0;
      float n00r = c2 * m00r - s2 * m10r, n00i = c2 * m00i - s2 * m10i;
      float n01r = c2 * m01r - s2 * m11r, n01i = c2 * m01i - s2 * m11i;
      float n10r = s2 * m00r + c2 * m10r, n10i = s2 * m00i + c2 * m10i;
      float n11r = s2 * m01r + c2 * m11r, n11i = s2 * m01i + c2 * m11i;
      m1[id * 2 + 0] = make_float4(c3 * n00r + s3 * n00i, c3 * n00i - s3 * n00r,
                                   c3 * n01r + s3 * n01i, c3 * n01i - s3 * n01r);
      m1[id * 2 + 1] = make_float4(c3 * n10r - s3 * n10i, c3 * n10i + s3 * n10r,
                                   c3 * n11r - s3 * n11i, c3 * n11i + s3 * n11r);
    } else {
      // U = RZ(a5) RY(a4)
      float s4, c4, s5, c5;
      sincosf(0.5f * a[44 + q], &s4, &c4);
      sincosf(0.5f * a[55 + q], &s5, &c5);
      m2[id * 2 + 0] = make_float4(c5 * c4, -s5 * c4, -c5 * s4, s5 * s4);
      m2[id * 2 + 1] = make_float4(c5 * s4,  s5 * s4,  c5 * c4, s5 * c4);
    }
  }
  __syncthreads();

  // state in registers: amp bits [2:0]=reg, [8:3]=lane, [10:9]=wave
  float sr[8], si[8];
#pragma unroll
  for (int i = 0; i < 8; ++i) { sr[i] = 0.f; si[i] = 0.f; }
  if (tid == 0) sr[0] = 1.f;

  for (int c = 0; c < NC; ++c) {
    const float4* M1 = &m1[c * NQ * 2];
    const float4* M2 = &m2[c * NQ * 2];
    // ---- single-qubit layer: q=0..10 -> bit 10..0 ----
    g_wave<2,false>(sr, si, loadU(M1 + 0 * 2), ex0, wave, lane, true);
    g_wave<1,false>(sr, si, loadU(M1 + 1 * 2), ex1, wave, lane, true);
    g_lane<5,false>(sr, si, loadU(M1 + 2 * 2), lane, false);
    g_lane<4,false>(sr, si, loadU(M1 + 3 * 2), lane, false);
    g_lane<3,false>(sr, si, loadU(M1 + 4 * 2), lane, false);
    g_lane<2,false>(sr, si, loadU(M1 + 5 * 2), lane, false);
    g_lane<1,false>(sr, si, loadU(M1 + 6 * 2), lane, false);
    g_lane<0,false>(sr, si, loadU(M1 + 7 * 2), lane, false);
    g_reg<2>(sr, si, loadU(M1 + 8 * 2));
    g_reg<1>(sr, si, loadU(M1 + 9 * 2));
    g_reg<0>(sr, si, loadU(M1 + 10 * 2));
    // ---- controlled layer: control bit 10-q, target bit 10-(q+1)%11 ----
    g_wave<1,false>(sr, si, loadU(M2 + 0 * 2), ex0, wave, lane, (wave & 2) != 0); // q=0: c=b10,t=b9
    g_lane<5,true >(sr, si, loadU(M2 + 1 * 2), lane, (wave & 1) != 0);            // q=1: c=b9,t=b8
    g_lane<4,true >(sr, si, loadU(M2 + 2 * 2), lane, (lane & 32) != 0);           // q=2: c=b8,t=b7
    g_lane<3,true >(sr, si, loadU(M2 + 3 * 2), lane, (lane & 16) != 0);           // q=3
    g_lane<2,true >(sr, si, loadU(M2 + 4 * 2), lane, (lane & 8) != 0);            // q=4
    g_lane<1,true >(sr, si, loadU(M2 + 5 * 2), lane, (lane & 4) != 0);            // q=5
    g_lane<0,true >(sr, si, loadU(M2 + 6 * 2), lane, (lane & 2) != 0);            // q=6
    g_clane_reg<2>(sr, si, loadU(M2 + 7 * 2), (lane & 1) != 0);                   // q=7: c=b3,t=b2
    g_creg<2,1>(sr, si, loadU(M2 + 8 * 2));                                       // q=8
    g_creg<1,0>(sr, si, loadU(M2 + 9 * 2));                                       // q=9
    g_wave<2,true >(sr, si, loadU(M2 + 10 * 2), ex1, wave, lane, true);           // q=10: c=b0,t=b10
  }

  // ---- expectations ----
  const int base = (wave << 6) | lane;
#pragma unroll
  for (int i = 0; i < 8; ++i) ex0[(i << 8) | base] = make_float2(sr[i], si[i]);
  __syncthreads();
  const int pb1 = ((wave ^ 1) << 6) | lane;
  const int pb2 = ((wave ^ 2) << 6) | lane;
  float x9 = 0.f, x10 = 0.f;
#pragma unroll
  for (int i = 0; i < 8; ++i) {
    const float2 p1 = ex0[(i << 8) | pb1];
    const float2 p2 = ex0[(i << 8) | pb2];
    x9  += sr[i] * p1.x + si[i] * p1.y;
    x10 += sr[i] * p2.x + si[i] * p2.y;
  }
  float mg[8];
#pragma unroll
  for (int i = 0; i < 8; ++i) mg[i] = sr[i] * sr[i] + si[i] * si[i];
  const float ztot = ((mg[0]+mg[1])+(mg[2]+mg[3]))+((mg[4]+mg[5])+(mg[6]+mg[7]));
  const float z0 = (mg[0]-mg[1])+(mg[2]-mg[3])+(mg[4]-mg[5])+(mg[6]-mg[7]);
  const float z1 = (mg[0]+mg[1])-(mg[2]+mg[3])+(mg[4]+mg[5])-(mg[6]+mg[7]);
  const float z2 = (mg[0]+mg[1])+(mg[2]+mg[3])-(mg[4]+mg[5])-(mg[6]+mg[7]);
  float x0 = 0.f, x1 = 0.f, x2 = 0.f;
#pragma unroll
  for (int i = 0; i < 8; ++i) {
    x0 += sr[i] * sr[i ^ 1] + si[i] * si[i ^ 1];
    x1 += sr[i] * sr[i ^ 2] + si[i] * si[i ^ 2];
    x2 += sr[i] * sr[i ^ 4] + si[i] * si[i ^ 4];
  }
  float xl0=0.f, xl1=0.f, xl2=0.f, xl3=0.f, xl4=0.f, xl5=0.f;
#pragma unroll
  for (int i = 0; i < 8; ++i) {
    xl0 += sr[i]*__shfl_xor(sr[i], 1, 64)  + si[i]*__shfl_xor(si[i], 1, 64);
    xl1 += sr[i]*__shfl_xor(sr[i], 2, 64)  + si[i]*__shfl_xor(si[i], 2, 64);
    xl2 += sr[i]*__shfl_xor(sr[i], 4, 64)  + si[i]*__shfl_xor(si[i], 4, 64);
    xl3 += sr[i]*__shfl_xor(sr[i], 8, 64)  + si[i]*__shfl_xor(si[i], 8, 64);
    xl4 += sr[i]*__shfl_xor(sr[i], 16, 64) + si[i]*__shfl_xor(si[i], 16, 64);
    xl5 += sr[i]*__shfl_xor(sr[i], 32, 64) + si[i]*__shfl_xor(si[i], 32, 64);
  }
  const float zq0 = (wave & 2) ? -ztot : ztot;   // bit10 -> qubit 0
  const float zq1 = (wave & 1) ? -ztot : ztot;   // bit9  -> qubit 1
  const float zl5 = (lane & 32) ? -ztot : ztot;  // bit8  -> qubit 2
  const float zl4 = (lane & 16) ? -ztot : ztot;
  const float zl3 = (lane & 8)  ? -ztot : ztot;
  const float zl2 = (lane & 4)  ? -ztot : ztot;
  const float zl1 = (lane & 2)  ? -ztot : ztot;
  const float zl0 = (lane & 1)  ? -ztot : ztot;  // bit3  -> qubit 7

  float v[22];
  v[0]=x10; v[1]=x9; v[2]=xl5; v[3]=xl4; v[4]=xl3; v[5]=xl2; v[6]=xl1; v[7]=xl0;
  v[8]=x2; v[9]=x1; v[10]=x0;
  v[11]=zq0; v[12]=zq1; v[13]=zl5; v[14]=zl4; v[15]=zl3; v[16]=zl2; v[17]=zl1; v[18]=zl0;
  v[19]=z2; v[20]=z1; v[21]=z0;
#pragma unroll
  for (int k = 0; k < 22; ++k) {
#pragma unroll
    for (int off = 32; off; off >>= 1) v[k] += __shfl_xor(v[k], off, 64);
  }
  if (lane == 0) {
#pragma unroll
    for (int k = 0; k < 22; ++k) red[wave][k] = v[k];
  }
  __syncthreads();
  if (tid < 22) {
    out[bidx * 22 + tid] = red[0][tid] + red[1][tid] + red[2][tid] + red[3][tid];
  }
}

extern "C" void kernel_launch(void* const* d_in, const int* in_sizes, int n_in,
                              void* d_out, int out_size, void* d_ws, size_t ws_size,
                              hipStream_t stream) {
  (void)n_in; (void)d_ws; (void)ws_size; (void)out_size;
  const float* x = (const float*)d_in[0];
  const float* W = (const float*)d_in[1];
  const float* b = (const float*)d_in[2];
  float* out = (float*)d_out;
  const int batch = in_sizes[0] / NQ;
  qsim_kernel<<<batch, BLOCK, 0, stream>>>(x, W, b, out);
}